// Round 4
// baseline (469.685 us; speedup 1.0000x reference)
//
#include <hip/hip_runtime.h>
#include <hip/hip_bf16.h>

typedef unsigned long long ull;
typedef __attribute__((ext_vector_type(8))) short short8;
typedef __attribute__((ext_vector_type(8))) unsigned short us8;
typedef __attribute__((ext_vector_type(4))) unsigned short us4;
typedef __attribute__((ext_vector_type(4))) float f32x4;

constexpr int NN = 4096;   // nodes
constexpr int HH = 4;      // heads
constexpr int DD = 128;    // per-head dim
constexpr int NW = 64;     // 64-j tiles (= 64-bit mask words) per row

// float -> bf16 RTNE
__device__ inline unsigned short f2bf(float x) {
  unsigned u = __float_as_uint(x);
  u += 0x7FFFu + ((u >> 16) & 1u);
  return (unsigned short)(u >> 16);
}

// async 16B global->LDS (DMA; LDS dest = wave-uniform base + lane*16)
__device__ inline void gload16(const void* g, void* l) {
  __builtin_amdgcn_global_load_lds(
      (const __attribute__((address_space(1))) unsigned int*)g,
      (__attribute__((address_space(3))) unsigned int*)l, 16, 0, 0);
}

// ---------------------------------------------------------------------------
// adj (int32) -> transposed bitmask mbT[w][i] (bits j = w*64..w*64+63 of row i)
// ---------------------------------------------------------------------------
__global__ __launch_bounds__(256) void pack_mask_kernel(const int* __restrict__ adj,
                                                        ull* __restrict__ mbT) {
  const int i    = blockIdx.x;
  const int lane = threadIdx.x & 63;
  const int wave = threadIdx.x >> 6;
  for (int w = wave; w < NW; w += 4) {
    int v = adj[(size_t)i * NN + w * 64 + lane];
    ull m = __ballot(v > 0);
    if (lane == 0) mbT[(size_t)w * NN + i] = m;
  }
}

// ---------------------------------------------------------------------------
// fp32 -> bf16 elementwise (8/thread)
// ---------------------------------------------------------------------------
__global__ __launch_bounds__(256) void cvt_bf16_kernel(const float* __restrict__ in,
                                                       unsigned short* __restrict__ out,
                                                       int n8) {
  int i = blockIdx.x * 256 + threadIdx.x;
  if (i >= n8) return;
  f32x4 a = *(const f32x4*)(in + i * 8);
  f32x4 b = *(const f32x4*)(in + i * 8 + 4);
  us8 v;
#pragma unroll
  for (int q = 0; q < 4; ++q) { v[q] = f2bf(a[q]); v[q + 4] = f2bf(b[q]); }
  *(us8*)(out + i * 8) = v;
}

// ---------------------------------------------------------------------------
// W [H][K][128] fp32 -> WT bf16, tile-major swizzled: [h][kt][c][kc^ (c&7)][8]
// (so gemm can DMA a 16KB k-tile linearly and ds_read b-frags conflict-free)
// ---------------------------------------------------------------------------
__global__ __launch_bounds__(256) void prep_w_kernel(const float* __restrict__ W,
                                                     unsigned short* __restrict__ WT,
                                                     int KT) {
  int id = blockIdx.x * 256 + threadIdx.x;
  int total = HH * KT * 128 * 8;
  if (id >= total) return;
  int kc = id & 7;
  int c  = (id >> 3) & 127;
  int kt = (id >> 10) % KT;
  int h  = id / (KT * 1024);
  int K  = KT * 64;
  const float* src = W + ((size_t)h * K + kt * 64 + kc * 8) * 128 + c;
  us8 v;
#pragma unroll
  for (int e = 0; e < 8; ++e) v[e] = f2bf(src[(size_t)e * 128]);
  *(us8*)(WT + (((size_t)(h * KT + kt) * 128 + c) * 64 + ((kc ^ (c & 7)) * 8))) = v;
}

// ---------------------------------------------------------------------------
// MFMA GEMM: Wh[h] = A_h(bf16) @ W_h(bf16), 64 rows x 128 cols per block,
// 8 waves (16r x 64c each).  Outputs:
//   WhT  : bf16 tile-major swizzled [h][jtile][c][g^(c&7)][8]  (for att DMA)
//   src/dst : fp32 Wh.a reductions from the fp32 accumulators
// A staged via global_load_lds with inverse-swizzled per-lane SOURCE addrs;
// W staged linearly (pre-swizzled by prep_w).  Double-buffered, 1 barrier/tile.
// ---------------------------------------------------------------------------
__global__ __launch_bounds__(512) void gemm_mfma_kernel(
    const unsigned short* __restrict__ A, int sA, long hsA,
    const unsigned short* __restrict__ WT, int KT,
    unsigned short* __restrict__ WhT, const float* __restrict__ avec,
    float* __restrict__ srcO, float* __restrict__ dstO) {
  __shared__ unsigned short Al[2][64 * 64];    // 16KB: [row][kchunk^(row&7)]
  __shared__ unsigned short Wl[2][128 * 64];   // 32KB: [c][kchunk^(c&7)]
  __shared__ float sdred[2][64][2];
  const int t   = threadIdx.x;
  const int h   = blockIdx.y;
  const int i0  = blockIdx.x * 64;
  const int l   = t & 63;
  const int wv  = t >> 6;
  const int l15 = l & 15;
  const int l16 = l >> 4;
  const int wr  = (wv >> 1) * 16;
  const int wc  = (wv & 1) * 64;
  const unsigned short* Ab = A + (size_t)h * hsA;
  const unsigned short* Wb = WT + (size_t)h * KT * 8192;

  const int arowA = wv * 8 + (l >> 3);  // A-staging row for this lane's chunk
  const int agA   = l & 7;              // lds chunk slot

  f32x4 acc[4];
#pragma unroll
  for (int cf = 0; cf < 4; ++cf) acc[cf] = (f32x4){0.f, 0.f, 0.f, 0.f};

#define G_STAGE(kt_, b_)                                                          \
  {                                                                               \
    gload16(Ab + (size_t)(i0 + arowA) * sA + (kt_) * 64 + ((agA ^ (arowA & 7)) * 8), \
            &Al[b_][(wv * 64) * 8]);                                              \
    const unsigned short* wt = Wb + (size_t)(kt_)*8192;                           \
    gload16(wt + (size_t)(wv * 64 + l) * 8, &Wl[b_][(wv * 64) * 8]);              \
    gload16(wt + (size_t)(512 + wv * 64 + l) * 8, &Wl[b_][(512 + wv * 64) * 8]);  \
  }

  G_STAGE(0, 0);
  __syncthreads();
  int buf = 0;
  for (int kt = 0; kt < KT; ++kt) {
    if (kt + 1 < KT) G_STAGE(kt + 1, buf ^ 1);
    const int arow = wr + l15;
#pragma unroll
    for (int s = 0; s < 2; ++s) {
      int kc = s * 4 + l16;
      short8 a = *(const short8*)&Al[buf][arow * 64 + ((kc ^ (arow & 7)) * 8)];
#pragma unroll
      for (int cf = 0; cf < 4; ++cf) {
        int c = wc + cf * 16 + l15;
        short8 b = *(const short8*)&Wl[buf][c * 64 + ((kc ^ (c & 7)) * 8)];
        acc[cf] = __builtin_amdgcn_mfma_f32_16x16x32_bf16(a, b, acc[cf], 0, 0, 0);
      }
    }
    __syncthreads();
    buf ^= 1;
  }

  // ---- epilogue 1: WhT tiled-swizzled bf16 store (4 consecutive j per pack)
  const int wblk = i0 >> 6;
  const int g    = (wr >> 3) + (l16 >> 1);
  const int eoff = (l16 * 4) & 7;
#pragma unroll
  for (int cf = 0; cf < 4; ++cf) {
    int c = wc + cf * 16 + l15;
    us4 pk;
#pragma unroll
    for (int r = 0; r < 4; ++r) pk[r] = f2bf(acc[cf][r]);
    *(us4*)(WhT + (((size_t)(h * 64 + wblk) * 128 + c) * 64 + ((g ^ (c & 7)) * 8) + eoff)) = pk;
  }

  // ---- epilogue 2: src/dst = Wh . a (fp32, from accumulators)
  float ps[4] = {0.f, 0.f, 0.f, 0.f}, pd[4] = {0.f, 0.f, 0.f, 0.f};
#pragma unroll
  for (int cf = 0; cf < 4; ++cf) {
    int c = wc + cf * 16 + l15;
    float as = avec[h * 2 * DD + c];
    float ad = avec[h * 2 * DD + DD + c];
#pragma unroll
    for (int r = 0; r < 4; ++r) { ps[r] += acc[cf][r] * as; pd[r] += acc[cf][r] * ad; }
  }
#pragma unroll
  for (int off = 1; off < 16; off <<= 1) {
#pragma unroll
    for (int r = 0; r < 4; ++r) {
      ps[r] += __shfl_xor(ps[r], off, 64);
      pd[r] += __shfl_xor(pd[r], off, 64);
    }
  }
  if (l15 == 0) {
#pragma unroll
    for (int r = 0; r < 4; ++r) {
      sdred[wv & 1][wr + l16 * 4 + r][0] = ps[r];
      sdred[wv & 1][wr + l16 * 4 + r][1] = pd[r];
    }
  }
  __syncthreads();
  if (t < 128) {
    int row = t >> 1, sel = t & 1;
    float v = sdred[0][row][sel] + sdred[1][row][sel];
    (sel ? dstO : srcO)[(h << 12) + i0 + row] = v;
  }
#undef G_STAGE
}

// ---------------------------------------------------------------------------
// Stats: madj[g] = m + log(sum exp(e - m)),  m = max_j e_ij.
// lrelu is monotone -> m = lrelu(s_i + max masked d_j)  (pass 1, no exp).
// Pass 2: one expf per element.  All-masked row: m=-9e15, sum=N (uniform).
// ---------------------------------------------------------------------------
__global__ __launch_bounds__(256) void stats_kernel(const float* __restrict__ src,
                                                    const float* __restrict__ dst,
                                                    const ull* __restrict__ mbT,
                                                    float* __restrict__ madj) {
  const int g    = blockIdx.x * 4 + (threadIdx.x >> 6);
  const int lane = threadIdx.x & 63;
  const int h    = g >> 12;
  const int i    = g & (NN - 1);
  const float* dh = dst + (h << 12);
  const float si  = src[g];
  float M = -3.0e38f;
  for (int w = 0; w < NW; ++w) {
    ull bits = mbT[(size_t)w * NN + i];
    float d = dh[w * 64 + lane];
    M = fmaxf(M, ((bits >> lane) & 1ull) ? d : -3.0e38f);
  }
#pragma unroll
  for (int off = 32; off > 0; off >>= 1) M = fmaxf(M, __shfl_xor(M, off, 64));
  float sm = si + M;
  float m  = (M > -1.0e37f) ? (sm > 0.f ? sm : 0.2f * sm) : -9e15f;
  float la = 0.f;
  for (int w = 0; w < NW; ++w) {
    ull bits = mbT[(size_t)w * NN + i];
    float e = si + dh[w * 64 + lane];
    e = e > 0.f ? e : 0.2f * e;
    e = ((bits >> lane) & 1ull) ? e : -9e15f;
    la += __expf(e - m);
  }
#pragma unroll
  for (int off = 32; off > 0; off >>= 1) la += __shfl_xor(la, off, 64);
  if (lane == 0) madj[g] = m + __logf(la);
}

// ---------------------------------------------------------------------------
// MFMA attention: out[i, h*128+c] = elu( sum_j p_ij Wh[j][c] ),
// p = exp(e - madj) generated DIRECTLY into A-fragment registers
// (lane: row = l&15, k-chunk = l>>4).  Wh tile DMA'd from tiled-swizzled WhT
// (linear dest, swizzled ds_read).  64 rows x 128 cols, 8 waves, dbuf,
// one barrier per 64-j tile.
// ---------------------------------------------------------------------------
template <int OUTBF>
__global__ __launch_bounds__(512) void att_mfma_kernel(
    const unsigned short* __restrict__ WhT, const float* __restrict__ src,
    const float* __restrict__ dst, const float* __restrict__ madj,
    const ull* __restrict__ mbT, void* __restrict__ outp, int outStride) {
  __shared__ unsigned short whl[2][128 * 64];  // 32KB dbuf
  const int t   = threadIdx.x;
  const int h   = blockIdx.y;
  const int i0  = blockIdx.x * 64;
  const int l   = t & 63;
  const int wv  = t >> 6;
  const int l15 = l & 15;
  const int l16 = l >> 4;
  const int wr  = (wv >> 1) * 16;
  const int wc  = (wv & 1) * 64;

  const int arow   = i0 + wr + l15;          // this lane's P row
  const float s_i  = src[(h << 12) + arow];
  const float ma_i = madj[(h << 12) + arow];
  const float* dh  = dst + (h << 12);
  const unsigned short* Wt = WhT + (size_t)(h * 64) * 8192;

  f32x4 acc[4];
#pragma unroll
  for (int cf = 0; cf < 4; ++cf) acc[cf] = (f32x4){0.f, 0.f, 0.f, 0.f};

#define A_STAGE(w_, b_)                                                   \
  {                                                                       \
    const unsigned short* gt = Wt + (size_t)(w_)*8192;                    \
    gload16(gt + (size_t)(wv * 64 + l) * 8, &whl[b_][(wv * 64) * 8]);     \
    gload16(gt + (size_t)(512 + wv * 64 + l) * 8, &whl[b_][(512 + wv * 64) * 8]); \
  }

  A_STAGE(0, 0);
  __syncthreads();
  int buf = 0;
  for (int w = 0; w < NW; ++w) {
    if (w + 1 < NW) A_STAGE(w + 1, buf ^ 1);
    // P-gen into A-frag registers
    ull mb = mbT[(size_t)w * NN + arow];
    short8 afr[2];
#pragma unroll
    for (int s = 0; s < 2; ++s) {
      int bsh = s * 32 + l16 * 8;
      f32x4 d0 = *(const f32x4*)(dh + w * 64 + bsh);
      f32x4 d1 = *(const f32x4*)(dh + w * 64 + bsh + 4);
      unsigned bits = (unsigned)((mb >> bsh) & 0xffull);
#pragma unroll
      for (int q = 0; q < 8; ++q) {
        float e = s_i + (q < 4 ? d0[q] : d1[q - 4]);
        e = e > 0.f ? e : 0.2f * e;
        e = ((bits >> q) & 1u) ? e : -9e15f;
        afr[s][q] = (short)f2bf(__expf(e - ma_i));
      }
    }
    // MFMA: 2 K-steps x 4 col-frags
#pragma unroll
    for (int s = 0; s < 2; ++s) {
      int kc = s * 4 + l16;
#pragma unroll
      for (int cf = 0; cf < 4; ++cf) {
        int c = wc + cf * 16 + l15;
        short8 b = *(const short8*)&whl[buf][c * 64 + ((kc ^ (c & 7)) * 8)];
        acc[cf] = __builtin_amdgcn_mfma_f32_16x16x32_bf16(afr[s], b, acc[cf], 0, 0, 0);
      }
    }
    __syncthreads();
    buf ^= 1;
  }
  // epilogue: D col = l&15, row = (l>>4)*4 + reg;  elu
#pragma unroll
  for (int cf = 0; cf < 4; ++cf) {
    int col = h * DD + wc + cf * 16 + l15;
#pragma unroll
    for (int r = 0; r < 4; ++r) {
      int row = i0 + wr + l16 * 4 + r;
      float v = acc[cf][r];
      v = v > 0.f ? v : __expf(v) - 1.f;
      if (OUTBF)
        ((unsigned short*)outp)[(size_t)row * outStride + col] = f2bf(v);
      else
        ((float*)outp)[(size_t)row * outStride + col] = v;
    }
  }
#undef A_STAGE
}

// ---------------------------------------------------------------------------
extern "C" void kernel_launch(void* const* d_in, const int* in_sizes, int n_in,
                              void* d_out, int out_size, void* d_ws, size_t ws_size,
                              hipStream_t stream) {
  const float* chems = (const float*)d_in[0];  // [H, N, 128]
  const int*   adj   = (const int*)d_in[1];    // [N, N]
  const float* W1    = (const float*)d_in[2];  // [H, 128, 128]
  const float* a1    = (const float*)d_in[3];  // [H, 256]
  const float* W2    = (const float*)d_in[4];  // [H, 512, 128]
  const float* a2    = (const float*)d_in[5];  // [H, 256]
  float* out = (float*)d_out;                  // [N, 512] fp32

  char* p = (char*)d_ws;
  auto alloc = [&](size_t bytes) { char* r = p; p += (bytes + 255) & ~255ull; return r; };
  ull*   mbT  = (ull*)alloc((size_t)NW * NN * 8);                        // 2 MB
  unsigned short* cbf  = (unsigned short*)alloc((size_t)HH * NN * DD * 2);   // 4 MB
  unsigned short* xbf  = (unsigned short*)alloc((size_t)NN * HH * DD * 2);   // 4 MB
  unsigned short* WhT1 = (unsigned short*)alloc((size_t)HH * 64 * 8192 * 2); // 4 MB
  unsigned short* WhT2 = (unsigned short*)alloc((size_t)HH * 64 * 8192 * 2); // 4 MB
  unsigned short* WT1  = (unsigned short*)alloc((size_t)HH * 2 * 8192 * 2);  // 128 KB
  unsigned short* WT2  = (unsigned short*)alloc((size_t)HH * 8 * 8192 * 2);  // 512 KB
  float* src1 = (float*)alloc((size_t)HH * NN * 4);
  float* dst1 = (float*)alloc((size_t)HH * NN * 4);
  float* mj1  = (float*)alloc((size_t)HH * NN * 4);
  float* src2 = (float*)alloc((size_t)HH * NN * 4);
  float* dst2 = (float*)alloc((size_t)HH * NN * 4);
  float* mj2  = (float*)alloc((size_t)HH * NN * 4);
  (void)ws_size; (void)in_sizes; (void)n_in; (void)out_size;

  pack_mask_kernel<<<NN, 256, 0, stream>>>(adj, mbT);
  cvt_bf16_kernel<<<(HH * NN * DD / 8 + 255) / 256, 256, 0, stream>>>(chems, cbf,
                                                                      HH * NN * DD / 8);
  prep_w_kernel<<<(HH * 2 * 1024 + 255) / 256, 256, 0, stream>>>(W1, WT1, 2);
  prep_w_kernel<<<(HH * 8 * 1024 + 255) / 256, 256, 0, stream>>>(W2, WT2, 8);

  // ---- stage 1 ----
  gemm_mfma_kernel<<<dim3(NN / 64, HH), 512, 0, stream>>>(
      cbf, DD, (long)NN * DD, WT1, 2, WhT1, a1, src1, dst1);
  stats_kernel<<<(HH * NN) / 4, 256, 0, stream>>>(src1, dst1, mbT, mj1);
  att_mfma_kernel<1><<<dim3(NN / 64, HH), 512, 0, stream>>>(
      WhT1, src1, dst1, mj1, mbT, xbf, HH * DD);
  // ---- stage 2 ----
  gemm_mfma_kernel<<<dim3(NN / 64, HH), 512, 0, stream>>>(
      xbf, HH * DD, 0L, WT2, 8, WhT2, a2, src2, dst2);
  stats_kernel<<<(HH * NN) / 4, 256, 0, stream>>>(src2, dst2, mbT, mj2);
  att_mfma_kernel<0><<<dim3(NN / 64, HH), 512, 0, stream>>>(
      WhT2, src2, dst2, mj2, mbT, out, HH * DD);
}

// Round 6
// 406.028 us; speedup vs baseline: 1.1568x; 1.1568x over previous
//
#include <hip/hip_runtime.h>
#include <hip/hip_bf16.h>

typedef unsigned long long ull;
typedef __attribute__((ext_vector_type(8))) short short8;
typedef __attribute__((ext_vector_type(8))) unsigned short us8;
typedef __attribute__((ext_vector_type(4))) unsigned short us4;
typedef __attribute__((ext_vector_type(4))) float f32x4;

constexpr int NN = 4096;   // nodes
constexpr int HH = 4;      // heads
constexpr int DD = 128;    // per-head dim
constexpr int NW = 64;     // 64-j tiles (= 64-bit mask words) per row
constexpr float L2E = 1.44269504088896f;

// float -> bf16 RTNE (manual; used in cold paths)
__device__ inline unsigned short f2bf(float x) {
  unsigned u = __float_as_uint(x);
  u += 0x7FFFu + ((u >> 16) & 1u);
  return (unsigned short)(u >> 16);
}

// float -> bf16 via native cast (compiler emits v_cvt_pk_bf16_f32 for pairs)
__device__ inline short fbf(float x) {
  __bf16 b = (__bf16)x;
  short r;
  __builtin_memcpy(&r, &b, 2);
  return r;
}

// async 16B global->LDS (DMA; LDS dest = wave-uniform base + lane*16)
__device__ inline void gload16(const void* g, void* l) {
  __builtin_amdgcn_global_load_lds(
      (const __attribute__((address_space(1))) unsigned int*)g,
      (__attribute__((address_space(3))) unsigned int*)l, 16, 0, 0);
}

// ---------------------------------------------------------------------------
// adj (int32) -> transposed bitmask mbT[w][i] (bits j = w*64..w*64+63 of row i)
// ---------------------------------------------------------------------------
__global__ __launch_bounds__(256) void pack_mask_kernel(const int* __restrict__ adj,
                                                        ull* __restrict__ mbT) {
  const int i    = blockIdx.x;
  const int lane = threadIdx.x & 63;
  const int wave = threadIdx.x >> 6;
  for (int w = wave; w < NW; w += 4) {
    int v = adj[(size_t)i * NN + w * 64 + lane];
    ull m = __ballot(v > 0);
    if (lane == 0) mbT[(size_t)w * NN + i] = m;
  }
}

// ---------------------------------------------------------------------------
// fp32 -> bf16 elementwise (8/thread)
// ---------------------------------------------------------------------------
__global__ __launch_bounds__(256) void cvt_bf16_kernel(const float* __restrict__ in,
                                                       unsigned short* __restrict__ out,
                                                       int n8) {
  int i = blockIdx.x * 256 + threadIdx.x;
  if (i >= n8) return;
  f32x4 a = *(const f32x4*)(in + i * 8);
  f32x4 b = *(const f32x4*)(in + i * 8 + 4);
  us8 v;
#pragma unroll
  for (int q = 0; q < 4; ++q) { v[q] = f2bf(a[q]); v[q + 4] = f2bf(b[q]); }
  *(us8*)(out + i * 8) = v;
}

// ---------------------------------------------------------------------------
// W [H][K][128] fp32 -> WT bf16, tile-major swizzled: [h][kt][c][kc^(c&7)][8]
// ---------------------------------------------------------------------------
__global__ __launch_bounds__(256) void prep_w_kernel(const float* __restrict__ W,
                                                     unsigned short* __restrict__ WT,
                                                     int KT) {
  int id = blockIdx.x * 256 + threadIdx.x;
  int total = HH * KT * 128 * 8;
  if (id >= total) return;
  int kc = id & 7;
  int c  = (id >> 3) & 127;
  int kt = (id >> 10) % KT;
  int h  = id / (KT * 1024);
  int K  = KT * 64;
  const float* src = W + ((size_t)h * K + kt * 64 + kc * 8) * 128 + c;
  us8 v;
#pragma unroll
  for (int e = 0; e < 8; ++e) v[e] = f2bf(src[(size_t)e * 128]);
  *(us8*)(WT + (((size_t)(h * KT + kt) * 128 + c) * 64 + ((kc ^ (c & 7)) * 8))) = v;
}

// ---------------------------------------------------------------------------
// MFMA GEMM (validated): Wh = A(bf16) @ W(bf16).
// Outputs WhT (tiled-swizzled bf16) + src/dst fp32 reductions.
// ---------------------------------------------------------------------------
__global__ __launch_bounds__(512) void gemm_mfma_kernel(
    const unsigned short* __restrict__ A, int sA, long hsA,
    const unsigned short* __restrict__ WT, int KT,
    unsigned short* __restrict__ WhT, const float* __restrict__ avec,
    float* __restrict__ srcO, float* __restrict__ dstO) {
  __shared__ unsigned short Al[2][64 * 64];
  __shared__ unsigned short Wl[2][128 * 64];
  __shared__ float sdred[2][64][2];
  const int t   = threadIdx.x;
  const int h   = blockIdx.y;
  const int i0  = blockIdx.x * 64;
  const int l   = t & 63;
  const int wv  = t >> 6;
  const int l15 = l & 15;
  const int l16 = l >> 4;
  const int wr  = (wv >> 1) * 16;
  const int wc  = (wv & 1) * 64;
  const unsigned short* Ab = A + (size_t)h * hsA;
  const unsigned short* Wb = WT + (size_t)h * KT * 8192;

  const int arowA = wv * 8 + (l >> 3);
  const int agA   = l & 7;

  f32x4 acc[4];
#pragma unroll
  for (int cf = 0; cf < 4; ++cf) acc[cf] = (f32x4){0.f, 0.f, 0.f, 0.f};

#define G_STAGE(kt_, b_)                                                          \
  {                                                                               \
    gload16(Ab + (size_t)(i0 + arowA) * sA + (kt_) * 64 + ((agA ^ (arowA & 7)) * 8), \
            &Al[b_][(wv * 64) * 8]);                                              \
    const unsigned short* wt = Wb + (size_t)(kt_)*8192;                           \
    gload16(wt + (size_t)(wv * 64 + l) * 8, &Wl[b_][(wv * 64) * 8]);              \
    gload16(wt + (size_t)(512 + wv * 64 + l) * 8, &Wl[b_][(512 + wv * 64) * 8]);  \
  }

  G_STAGE(0, 0);
  __syncthreads();
  int buf = 0;
  for (int kt = 0; kt < KT; ++kt) {
    if (kt + 1 < KT) G_STAGE(kt + 1, buf ^ 1);
    const int arow = wr + l15;
#pragma unroll
    for (int s = 0; s < 2; ++s) {
      int kc = s * 4 + l16;
      short8 a = *(const short8*)&Al[buf][arow * 64 + ((kc ^ (arow & 7)) * 8)];
#pragma unroll
      for (int cf = 0; cf < 4; ++cf) {
        int c = wc + cf * 16 + l15;
        short8 b = *(const short8*)&Wl[buf][c * 64 + ((kc ^ (c & 7)) * 8)];
        acc[cf] = __builtin_amdgcn_mfma_f32_16x16x32_bf16(a, b, acc[cf], 0, 0, 0);
      }
    }
    __syncthreads();
    buf ^= 1;
  }

  const int wblk = i0 >> 6;
  const int g    = (wr >> 3) + (l16 >> 1);
  const int eoff = (l16 * 4) & 7;
#pragma unroll
  for (int cf = 0; cf < 4; ++cf) {
    int c = wc + cf * 16 + l15;
    us4 pk;
#pragma unroll
    for (int r = 0; r < 4; ++r) pk[r] = f2bf(acc[cf][r]);
    *(us4*)(WhT + (((size_t)(h * 64 + wblk) * 128 + c) * 64 + ((g ^ (c & 7)) * 8) + eoff)) = pk;
  }

  float ps[4] = {0.f, 0.f, 0.f, 0.f}, pd[4] = {0.f, 0.f, 0.f, 0.f};
#pragma unroll
  for (int cf = 0; cf < 4; ++cf) {
    int c = wc + cf * 16 + l15;
    float as = avec[h * 2 * DD + c];
    float ad = avec[h * 2 * DD + DD + c];
#pragma unroll
    for (int r = 0; r < 4; ++r) { ps[r] += acc[cf][r] * as; pd[r] += acc[cf][r] * ad; }
  }
#pragma unroll
  for (int off = 1; off < 16; off <<= 1) {
#pragma unroll
    for (int r = 0; r < 4; ++r) {
      ps[r] += __shfl_xor(ps[r], off, 64);
      pd[r] += __shfl_xor(pd[r], off, 64);
    }
  }
  if (l15 == 0) {
#pragma unroll
    for (int r = 0; r < 4; ++r) {
      sdred[wv & 1][wr + l16 * 4 + r][0] = ps[r];
      sdred[wv & 1][wr + l16 * 4 + r][1] = pd[r];
    }
  }
  __syncthreads();
  if (t < 128) {
    int row = t >> 1, sel = t & 1;
    float v = sdred[0][row][sel] + sdred[1][row][sel];
    (sel ? dstO : srcO)[(h << 12) + i0 + row] = v;
  }
#undef G_STAGE
}

// ---------------------------------------------------------------------------
// Stats: per row g compute madj = m + log(sum exp(e-m)) internally, then emit
// prefolded constants for att's 3-op P math:
//   sM = (s - madj)*log2e, uM = (0.2 s - madj)*log2e, dL2 = d*log2e.
// lrelu monotone -> m = lrelu(s_i + max masked d_j).
// ---------------------------------------------------------------------------
__global__ __launch_bounds__(256) void stats_kernel(const float* __restrict__ src,
                                                    const float* __restrict__ dst,
                                                    const ull* __restrict__ mbT,
                                                    float* __restrict__ sM,
                                                    float* __restrict__ uM,
                                                    float* __restrict__ dL2) {
  const int g    = blockIdx.x * 4 + (threadIdx.x >> 6);
  const int lane = threadIdx.x & 63;
  const int h    = g >> 12;
  const int i    = g & (NN - 1);
  const float* dh = dst + (h << 12);
  const float si  = src[g];
  float M = -3.0e38f;
  for (int w = 0; w < NW; ++w) {
    ull bits = mbT[(size_t)w * NN + i];
    float d = dh[w * 64 + lane];
    M = fmaxf(M, ((bits >> lane) & 1ull) ? d : -3.0e38f);
  }
#pragma unroll
  for (int off = 32; off > 0; off >>= 1) M = fmaxf(M, __shfl_xor(M, off, 64));
  float sm = si + M;
  float m  = (M > -1.0e37f) ? (sm > 0.f ? sm : 0.2f * sm) : -9e15f;
  float la = 0.f;
  for (int w = 0; w < NW; ++w) {
    ull bits = mbT[(size_t)w * NN + i];
    float e = si + dh[w * 64 + lane];
    e = e > 0.f ? e : 0.2f * e;
    e = ((bits >> lane) & 1ull) ? e : -9e15f;
    la += __expf(e - m);
  }
#pragma unroll
  for (int off = 32; off > 0; off >>= 1) la += __shfl_xor(la, off, 64);
  if (lane == 0) {
    float ma = m + __logf(la);
    sM[g]  = (si - ma) * L2E;
    uM[g]  = (0.2f * si - ma) * L2E;
    dL2[g] = dst[g] * L2E;
  }
}

// ---------------------------------------------------------------------------
// MFMA attention PARTIAL: part[jh][g][c] = sum_{j in half jh} p_ij Wh[j][c].
// 64-row block, 4 waves = 4 ROW groups (each 16r x 128c, 8 C-frags) -> every
// p computed exactly once.  P math (prefolded, 2^z form):
//   t1 = sM + d;  t2 = fma(d, 0.2, uM);  z = max(t1,t2);  masked -> -1e30;
//   p = v_exp_f32(z);  bf16 via native cast (v_cvt_pk).
// Wh tile DMA'd from tiled-swizzled WhT; dbuf, 1 barrier/tile.
// ---------------------------------------------------------------------------
__global__ __launch_bounds__(256) void att_part_kernel(
    const unsigned short* __restrict__ WhT, const float* __restrict__ sM,
    const float* __restrict__ uM, const float* __restrict__ dL2,
    const ull* __restrict__ mbT, float* __restrict__ part) {
  __shared__ unsigned short whl[2][128 * 64];  // 32KB dbuf
  const int t   = threadIdx.x;
  const int h   = blockIdx.y;
  const int jh  = blockIdx.x & 1;
  const int i0  = (blockIdx.x >> 1) * 64;
  const int l   = t & 63;
  const int wv  = t >> 6;
  const int l15 = l & 15;
  const int l16 = l >> 4;
  const int wr  = wv * 16;

  const int arow  = i0 + wr + l15;
  const int gr    = (h << 12) + arow;
  const float s_i = sM[gr];
  const float u_i = uM[gr];
  const float* dj = dL2 + (h << 12);
  const unsigned short* Wt = WhT + (size_t)(h * 64) * 8192;
  const int w0 = jh * 32;

  f32x4 acc[8];
#pragma unroll
  for (int cf = 0; cf < 8; ++cf) acc[cf] = (f32x4){0.f, 0.f, 0.f, 0.f};

#define A_STAGE(w_, b_)                                                    \
  {                                                                        \
    const unsigned short* gt = Wt + (size_t)(w_)*8192;                     \
    gload16(gt + (size_t)(0 * 256 + t) * 8, &whl[b_][(0 * 256 + wv * 64) * 8]); \
    gload16(gt + (size_t)(1 * 256 + t) * 8, &whl[b_][(1 * 256 + wv * 64) * 8]); \
    gload16(gt + (size_t)(2 * 256 + t) * 8, &whl[b_][(2 * 256 + wv * 64) * 8]); \
    gload16(gt + (size_t)(3 * 256 + t) * 8, &whl[b_][(3 * 256 + wv * 64) * 8]); \
  }

  A_STAGE(w0, 0);
  __syncthreads();
  int buf = 0;
  for (int it = 0; it < 32; ++it) {
    const int w = w0 + it;
    if (it + 1 < 32) A_STAGE(w + 1, buf ^ 1);
    // P-gen directly into A-frag registers (lane: row=l15, kchunk=l16)
    ull mb = mbT[(size_t)w * NN + arow];
    short8 afr[2];
#pragma unroll
    for (int s = 0; s < 2; ++s) {
      const int bsh = s * 32 + l16 * 8;
      f32x4 d0 = *(const f32x4*)(dj + w * 64 + bsh);
      f32x4 d1 = *(const f32x4*)(dj + w * 64 + bsh + 4);
      unsigned mb8 = (unsigned)((mb >> bsh) & 0xffull);
#pragma unroll
      for (int q = 0; q < 8; ++q) {
        float d = (q < 4) ? d0[q] : d1[q - 4];
        float t1 = s_i + d;
        float t2 = __builtin_fmaf(d, 0.2f, u_i);
        float z = fmaxf(t1, t2);
        z = ((mb8 >> q) & 1u) ? z : -1.0e30f;
        afr[s][q] = fbf(__builtin_amdgcn_exp2f(z));
      }
    }
#pragma unroll
    for (int s = 0; s < 2; ++s) {
      int kc = s * 4 + l16;
#pragma unroll
      for (int cf = 0; cf < 8; ++cf) {
        int c = cf * 16 + l15;
        short8 b = *(const short8*)&whl[buf][c * 64 + ((kc ^ (c & 7)) * 8)];
        acc[cf] = __builtin_amdgcn_mfma_f32_16x16x32_bf16(afr[s], b, acc[cf], 0, 0, 0);
      }
    }
    __syncthreads();
    buf ^= 1;
  }
  // partial store (fp32): D col = l&15, row = (l>>4)*4 + reg
  float* pb = part + ((size_t)jh * (HH * NN) + (h << 12) + i0) * 128;
#pragma unroll
  for (int cf = 0; cf < 8; ++cf) {
#pragma unroll
    for (int r = 0; r < 4; ++r)
      pb[(size_t)(wr + l16 * 4 + r) * 128 + cf * 16 + l15] = acc[cf][r];
  }
#undef A_STAGE
}

// ---------------------------------------------------------------------------
// Fuse: out[node, h*128+c] = elu(part0 + part1).  OUTBF: bf16 (stage-1 x).
// ---------------------------------------------------------------------------
template <int OUTBF>
__global__ __launch_bounds__(256) void fuse_kernel(const float* __restrict__ part,
                                                   void* __restrict__ outp) {
  int idx = blockIdx.x * 256 + threadIdx.x;   // one f32x4 per thread
  int c4 = (idx & 31) * 4;
  int g = idx >> 5;
  int node = g & (NN - 1), h = g >> 12;
  f32x4 a = *(const f32x4*)(part + (size_t)g * 128 + c4);
  f32x4 b = *(const f32x4*)(part + (size_t)(HH * NN) * 128 + (size_t)g * 128 + c4);
  size_t o = (size_t)node * (HH * DD) + h * DD + c4;
#pragma unroll
  for (int r = 0; r < 4; ++r) {
    float v = a[r] + b[r];
    a[r] = v > 0.f ? v : __expf(v) - 1.f;
  }
  if (OUTBF) {
    us4 pk;
#pragma unroll
    for (int r = 0; r < 4; ++r) pk[r] = (unsigned short)fbf(a[r]);
    *(us4*)((unsigned short*)outp + o) = pk;
  } else {
    *(f32x4*)((float*)outp + o) = a;
  }
}

// ---------------------------------------------------------------------------
extern "C" void kernel_launch(void* const* d_in, const int* in_sizes, int n_in,
                              void* d_out, int out_size, void* d_ws, size_t ws_size,
                              hipStream_t stream) {
  const float* chems = (const float*)d_in[0];  // [H, N, 128]
  const int*   adj   = (const int*)d_in[1];    // [N, N]
  const float* W1    = (const float*)d_in[2];  // [H, 128, 128]
  const float* a1    = (const float*)d_in[3];  // [H, 256]
  const float* W2    = (const float*)d_in[4];  // [H, 512, 128]
  const float* a2    = (const float*)d_in[5];  // [H, 256]
  float* out = (float*)d_out;                  // [N, 512] fp32

  char* p = (char*)d_ws;
  auto alloc = [&](size_t bytes) { char* r = p; p += (bytes + 255) & ~255ull; return r; };
  ull*   mbT  = (ull*)alloc((size_t)NW * NN * 8);                        // 2 MB
  unsigned short* cbf  = (unsigned short*)alloc((size_t)HH * NN * DD * 2);   // 4 MB
  unsigned short* xbf  = (unsigned short*)alloc((size_t)NN * HH * DD * 2);   // 4 MB
  unsigned short* WhT1 = (unsigned short*)alloc((size_t)HH * 64 * 8192 * 2); // 4 MB
  unsigned short* WhT2 = (unsigned short*)alloc((size_t)HH * 64 * 8192 * 2); // 4 MB
  unsigned short* WT1  = (unsigned short*)alloc((size_t)HH * 2 * 8192 * 2);  // 128 KB
  unsigned short* WT2  = (unsigned short*)alloc((size_t)HH * 8 * 8192 * 2);  // 512 KB
  float* parts = (float*)alloc((size_t)2 * HH * NN * 128 * 4);           // 16 MB (reused)
  float* src1 = (float*)alloc((size_t)HH * NN * 4);
  float* dst1 = (float*)alloc((size_t)HH * NN * 4);
  float* sM1  = (float*)alloc((size_t)HH * NN * 4);
  float* uM1  = (float*)alloc((size_t)HH * NN * 4);
  float* dL1  = (float*)alloc((size_t)HH * NN * 4);
  float* src2 = (float*)alloc((size_t)HH * NN * 4);
  float* dst2 = (float*)alloc((size_t)HH * NN * 4);
  float* sM2  = (float*)alloc((size_t)HH * NN * 4);
  float* uM2  = (float*)alloc((size_t)HH * NN * 4);
  float* dL2  = (float*)alloc((size_t)HH * NN * 4);
  (void)ws_size; (void)in_sizes; (void)n_in; (void)out_size;

  pack_mask_kernel<<<NN, 256, 0, stream>>>(adj, mbT);
  cvt_bf16_kernel<<<(HH * NN * DD / 8 + 255) / 256, 256, 0, stream>>>(chems, cbf,
                                                                      HH * NN * DD / 8);
  prep_w_kernel<<<(HH * 2 * 1024 + 255) / 256, 256, 0, stream>>>(W1, WT1, 2);
  prep_w_kernel<<<(HH * 8 * 1024 + 255) / 256, 256, 0, stream>>>(W2, WT2, 8);

  const int FUSE_BLK = (HH * NN * DD / 4) / 256;  // 2048

  // ---- stage 1 ----
  gemm_mfma_kernel<<<dim3(NN / 64, HH), 512, 0, stream>>>(
      cbf, DD, (long)NN * DD, WT1, 2, WhT1, a1, src1, dst1);
  stats_kernel<<<(HH * NN) / 4, 256, 0, stream>>>(src1, dst1, mbT, sM1, uM1, dL1);
  att_part_kernel<<<dim3(2 * NN / 64, HH), 256, 0, stream>>>(
      WhT1, sM1, uM1, dL1, mbT, parts);
  fuse_kernel<1><<<FUSE_BLK, 256, 0, stream>>>(parts, xbf);
  // ---- stage 2 ----
  gemm_mfma_kernel<<<dim3(NN / 64, HH), 512, 0, stream>>>(
      xbf, HH * DD, 0L, WT2, 8, WhT2, a2, src2, dst2);
  stats_kernel<<<(HH * NN) / 4, 256, 0, stream>>>(src2, dst2, mbT, sM2, uM2, dL2);
  att_part_kernel<<<dim3(2 * NN / 64, HH), 256, 0, stream>>>(
      WhT2, sM2, uM2, dL2, mbT, parts);
  fuse_kernel<0><<<FUSE_BLK, 256, 0, stream>>>(parts, out);
}

// Round 9
// 253.042 us; speedup vs baseline: 1.8562x; 1.6046x over previous
//
#include <hip/hip_runtime.h>
#include <hip/hip_bf16.h>

typedef unsigned long long ull;
typedef __attribute__((ext_vector_type(8))) short short8;
typedef __attribute__((ext_vector_type(8))) unsigned short us8;
typedef __attribute__((ext_vector_type(4))) unsigned short us4;
typedef __attribute__((ext_vector_type(4))) float f32x4;

constexpr int NN = 4096;   // nodes
constexpr int HH = 4;      // heads
constexpr int DD = 128;    // per-head dim
constexpr int NW = 64;     // 64-j tiles (= 64-bit mask words) per row
constexpr float L2E = 1.44269504088896f;

// float -> bf16 RTNE (manual; used in cold paths)
__device__ inline unsigned short f2bf(float x) {
  unsigned u = __float_as_uint(x);
  u += 0x7FFFu + ((u >> 16) & 1u);
  return (unsigned short)(u >> 16);
}

// float -> bf16 via native cast (compiler emits v_cvt_pk_bf16_f32 for pairs)
__device__ inline short fbf(float x) {
  __bf16 b = (__bf16)x;
  short r;
  __builtin_memcpy(&r, &b, 2);
  return r;
}

// async 16B global->LDS (DMA; LDS dest = wave-uniform base + lane*16)
__device__ inline void gload16(const void* g, void* l) {
  __builtin_amdgcn_global_load_lds(
      (const __attribute__((address_space(1))) unsigned int*)g,
      (__attribute__((address_space(3))) unsigned int*)l, 16, 0, 0);
}

// ---------------------------------------------------------------------------
// adj (int32) -> transposed bitmask mbT[w][i] (bits j = w*64..w*64+63 of row i)
// ---------------------------------------------------------------------------
__global__ __launch_bounds__(256) void pack_mask_kernel(const int* __restrict__ adj,
                                                        ull* __restrict__ mbT) {
  const int i    = blockIdx.x;
  const int lane = threadIdx.x & 63;
  const int wave = threadIdx.x >> 6;
  for (int w = wave; w < NW; w += 4) {
    int v = adj[(size_t)i * NN + w * 64 + lane];
    ull m = __ballot(v > 0);
    if (lane == 0) mbT[(size_t)w * NN + i] = m;
  }
}

// ---------------------------------------------------------------------------
// fp32 -> bf16 elementwise (8/thread)
// ---------------------------------------------------------------------------
__global__ __launch_bounds__(256) void cvt_bf16_kernel(const float* __restrict__ in,
                                                       unsigned short* __restrict__ out,
                                                       int n8) {
  int i = blockIdx.x * 256 + threadIdx.x;
  if (i >= n8) return;
  f32x4 a = *(const f32x4*)(in + i * 8);
  f32x4 b = *(const f32x4*)(in + i * 8 + 4);
  us8 v;
#pragma unroll
  for (int q = 0; q < 4; ++q) { v[q] = f2bf(a[q]); v[q + 4] = f2bf(b[q]); }
  *(us8*)(out + i * 8) = v;
}

// ---------------------------------------------------------------------------
// W [H][K][128] fp32 -> WT bf16, tile-major swizzled: [h][kt][c][kc^(c&7)][8]
// ---------------------------------------------------------------------------
__global__ __launch_bounds__(256) void prep_w_kernel(const float* __restrict__ W,
                                                     unsigned short* __restrict__ WT,
                                                     int KT) {
  int id = blockIdx.x * 256 + threadIdx.x;
  int total = HH * KT * 128 * 8;
  if (id >= total) return;
  int kc = id & 7;
  int c  = (id >> 3) & 127;
  int kt = (id >> 10) % KT;
  int h  = id / (KT * 1024);
  int K  = KT * 64;
  const float* src = W + ((size_t)h * K + kt * 64 + kc * 8) * 128 + c;
  us8 v;
#pragma unroll
  for (int e = 0; e < 8; ++e) v[e] = f2bf(src[(size_t)e * 128]);
  *(us8*)(WT + (((size_t)(h * KT + kt) * 128 + c) * 64 + ((kc ^ (c & 7)) * 8))) = v;
}

// ---------------------------------------------------------------------------
// MFMA GEMM (validated): Wh = A(bf16) @ W(bf16).
// Outputs WhT (tiled-swizzled bf16) + srcL/dstL = (Wh.a)*log2e  fp32.
// (Pre-scaled by log2e so att's P-gen is pure exp2 with homogeneous lrelu.)
// ---------------------------------------------------------------------------
__global__ __launch_bounds__(512) void gemm_mfma_kernel(
    const unsigned short* __restrict__ A, int sA, long hsA,
    const unsigned short* __restrict__ WT, int KT,
    unsigned short* __restrict__ WhT, const float* __restrict__ avec,
    float* __restrict__ srcO, float* __restrict__ dstO) {
  __shared__ unsigned short Al[2][64 * 64];
  __shared__ unsigned short Wl[2][128 * 64];
  __shared__ float sdred[2][64][2];
  const int t   = threadIdx.x;
  const int h   = blockIdx.y;
  const int i0  = blockIdx.x * 64;
  const int l   = t & 63;
  const int wv  = t >> 6;
  const int l15 = l & 15;
  const int l16 = l >> 4;
  const int wr  = (wv >> 1) * 16;
  const int wc  = (wv & 1) * 64;
  const unsigned short* Ab = A + (size_t)h * hsA;
  const unsigned short* Wb = WT + (size_t)h * KT * 8192;

  const int arowA = wv * 8 + (l >> 3);
  const int agA   = l & 7;

  f32x4 acc[4];
#pragma unroll
  for (int cf = 0; cf < 4; ++cf) acc[cf] = (f32x4){0.f, 0.f, 0.f, 0.f};

#define G_STAGE(kt_, b_)                                                          \
  {                                                                               \
    gload16(Ab + (size_t)(i0 + arowA) * sA + (kt_) * 64 + ((agA ^ (arowA & 7)) * 8), \
            &Al[b_][(wv * 64) * 8]);                                              \
    const unsigned short* wt = Wb + (size_t)(kt_)*8192;                           \
    gload16(wt + (size_t)(wv * 64 + l) * 8, &Wl[b_][(wv * 64) * 8]);              \
    gload16(wt + (size_t)(512 + wv * 64 + l) * 8, &Wl[b_][(512 + wv * 64) * 8]);  \
  }

  G_STAGE(0, 0);
  __syncthreads();
  int buf = 0;
  for (int kt = 0; kt < KT; ++kt) {
    if (kt + 1 < KT) G_STAGE(kt + 1, buf ^ 1);
    const int arow = wr + l15;
#pragma unroll
    for (int s = 0; s < 2; ++s) {
      int kc = s * 4 + l16;
      short8 a = *(const short8*)&Al[buf][arow * 64 + ((kc ^ (arow & 7)) * 8)];
#pragma unroll
      for (int cf = 0; cf < 4; ++cf) {
        int c = wc + cf * 16 + l15;
        short8 b = *(const short8*)&Wl[buf][c * 64 + ((kc ^ (c & 7)) * 8)];
        acc[cf] = __builtin_amdgcn_mfma_f32_16x16x32_bf16(a, b, acc[cf], 0, 0, 0);
      }
    }
    __syncthreads();
    buf ^= 1;
  }

  const int wblk = i0 >> 6;
  const int g    = (wr >> 3) + (l16 >> 1);
  const int eoff = (l16 * 4) & 7;
#pragma unroll
  for (int cf = 0; cf < 4; ++cf) {
    int c = wc + cf * 16 + l15;
    us4 pk;
#pragma unroll
    for (int r = 0; r < 4; ++r) pk[r] = f2bf(acc[cf][r]);
    *(us4*)(WhT + (((size_t)(h * 64 + wblk) * 128 + c) * 64 + ((g ^ (c & 7)) * 8) + eoff)) = pk;
  }

  float ps[4] = {0.f, 0.f, 0.f, 0.f}, pd[4] = {0.f, 0.f, 0.f, 0.f};
#pragma unroll
  for (int cf = 0; cf < 4; ++cf) {
    int c = wc + cf * 16 + l15;
    float as = avec[h * 2 * DD + c];
    float ad = avec[h * 2 * DD + DD + c];
#pragma unroll
    for (int r = 0; r < 4; ++r) { ps[r] += acc[cf][r] * as; pd[r] += acc[cf][r] * ad; }
  }
#pragma unroll
  for (int off = 1; off < 16; off <<= 1) {
#pragma unroll
    for (int r = 0; r < 4; ++r) {
      ps[r] += __shfl_xor(ps[r], off, 64);
      pd[r] += __shfl_xor(pd[r], off, 64);
    }
  }
  if (l15 == 0) {
#pragma unroll
    for (int r = 0; r < 4; ++r) {
      sdred[wv & 1][wr + l16 * 4 + r][0] = ps[r];
      sdred[wv & 1][wr + l16 * 4 + r][1] = pd[r];
    }
  }
  __syncthreads();
  if (t < 128) {
    int row = t >> 1, sel = t & 1;
    float v = (sdred[0][row][sel] + sdred[1][row][sel]) * L2E;
    (sel ? dstO : srcO)[(h << 12) + i0 + row] = v;
  }
#undef G_STAGE
}

// ---------------------------------------------------------------------------
// MFMA attention PARTIAL, UNNORMALIZED (softmax shift-invariance: no madj).
//   p_ij = exp2( masked( max(t, 0.2t) ) ),  t = sL_i + dL_j  (both *log2e)
//   part[jh][g][c] = sum_{j in half} p_ij Wh[j][c]
//   sums[jh][g]    = sum_{j in half} p_ij        (fp32, alongside MFMA)
// Normalization + elu happen in fuse (division by total sum -> convex comb,
// bf16 weight-rounding largely cancels).  64-row block, 4 row-waves, every p
// computed once.  Wh tile DMA'd from tiled-swizzled WhT; dbuf, 1 barrier/tile.
// ---------------------------------------------------------------------------
__global__ __launch_bounds__(256) void att_part_kernel(
    const unsigned short* __restrict__ WhT, const float* __restrict__ sL,
    const float* __restrict__ dL, const ull* __restrict__ mbT,
    float* __restrict__ part, float* __restrict__ sums) {
  __shared__ unsigned short whl[2][128 * 64];  // 32KB dbuf
  const int t   = threadIdx.x;
  const int h   = blockIdx.y;
  const int jh  = blockIdx.x & 1;
  const int i0  = (blockIdx.x >> 1) * 64;
  const int l   = t & 63;
  const int wv  = t >> 6;
  const int l15 = l & 15;
  const int l16 = l >> 4;
  const int wr  = wv * 16;

  const int arow  = i0 + wr + l15;
  const int gr    = (h << 12) + arow;
  const float s_i = sL[gr];
  const float* dj = dL + (h << 12);
  const unsigned short* Wt = WhT + (size_t)(h * 64) * 8192;
  const int w0 = jh * 32;

  f32x4 acc[8];
#pragma unroll
  for (int cf = 0; cf < 8; ++cf) acc[cf] = (f32x4){0.f, 0.f, 0.f, 0.f};
  float psum = 0.f;

#define A_STAGE(w_, b_)                                                    \
  {                                                                        \
    const unsigned short* gt = Wt + (size_t)(w_)*8192;                     \
    gload16(gt + (size_t)(0 * 256 + t) * 8, &whl[b_][(0 * 256 + wv * 64) * 8]); \
    gload16(gt + (size_t)(1 * 256 + t) * 8, &whl[b_][(1 * 256 + wv * 64) * 8]); \
    gload16(gt + (size_t)(2 * 256 + t) * 8, &whl[b_][(2 * 256 + wv * 64) * 8]); \
    gload16(gt + (size_t)(3 * 256 + t) * 8, &whl[b_][(3 * 256 + wv * 64) * 8]); \
  }

  A_STAGE(w0, 0);
  __syncthreads();
  int buf = 0;
  for (int it = 0; it < 32; ++it) {
    const int w = w0 + it;
    if (it + 1 < 32) A_STAGE(w + 1, buf ^ 1);
    // P-gen directly into A-frag registers (lane: row=l15, kchunk=l16)
    ull mb = mbT[(size_t)w * NN + arow];
    short8 afr[2];
#pragma unroll
    for (int s = 0; s < 2; ++s) {
      const int bsh = s * 32 + l16 * 8;
      f32x4 d0 = *(const f32x4*)(dj + w * 64 + bsh);
      f32x4 d1 = *(const f32x4*)(dj + w * 64 + bsh + 4);
      unsigned mb8 = (unsigned)((mb >> bsh) & 0xffull);
#pragma unroll
      for (int q = 0; q < 8; ++q) {
        float tt = s_i + ((q < 4) ? d0[q] : d1[q - 4]);
        float z = fmaxf(tt, 0.2f * tt);          // lrelu, homogeneous in log2e
        z = ((mb8 >> q) & 1u) ? z : -1.0e30f;    // masked -> p = 0
        float pf = __builtin_amdgcn_exp2f(z);
        psum += pf;
        afr[s][q] = fbf(pf);
      }
    }
#pragma unroll
    for (int s = 0; s < 2; ++s) {
      int kc = s * 4 + l16;
#pragma unroll
      for (int cf = 0; cf < 8; ++cf) {
        int c = cf * 16 + l15;
        short8 b = *(const short8*)&whl[buf][c * 64 + ((kc ^ (c & 7)) * 8)];
        acc[cf] = __builtin_amdgcn_mfma_f32_16x16x32_bf16(afr[s], b, acc[cf], 0, 0, 0);
      }
    }
    __syncthreads();
    buf ^= 1;
  }
  // row-sum reduce: lanes {l15, l15+16, l15+32, l15+48} hold same row
  psum += __shfl_xor(psum, 16, 64);
  psum += __shfl_xor(psum, 32, 64);
  if (l16 == 0) sums[(size_t)jh * (HH * NN) + gr] = psum;
  // partial store (fp32): D col = l&15, row = (l>>4)*4 + reg
  float* pb = part + ((size_t)jh * (HH * NN) + (h << 12) + i0) * 128;
#pragma unroll
  for (int cf = 0; cf < 8; ++cf) {
#pragma unroll
    for (int r = 0; r < 4; ++r)
      pb[(size_t)(wr + l16 * 4 + r) * 128 + cf * 16 + l15] = acc[cf][r];
  }
#undef A_STAGE
}

// ---------------------------------------------------------------------------
// Fuse: out[node, h*128+c] = elu( (part0+part1) / (sum0+sum1) ).
// OUTBF: bf16 (stage-1 x).
// ---------------------------------------------------------------------------
template <int OUTBF>
__global__ __launch_bounds__(256) void fuse_kernel(const float* __restrict__ part,
                                                   const float* __restrict__ sums,
                                                   void* __restrict__ outp) {
  int idx = blockIdx.x * 256 + threadIdx.x;   // one f32x4 per thread
  int c4 = (idx & 31) * 4;
  int g = idx >> 5;
  int node = g & (NN - 1), h = g >> 12;
  f32x4 a = *(const f32x4*)(part + (size_t)g * 128 + c4);
  f32x4 b = *(const f32x4*)(part + (size_t)(HH * NN) * 128 + (size_t)g * 128 + c4);
  float inv = 1.0f / (sums[g] + sums[HH * NN + g]);
  size_t o = (size_t)node * (HH * DD) + h * DD + c4;
#pragma unroll
  for (int r = 0; r < 4; ++r) {
    float v = (a[r] + b[r]) * inv;
    a[r] = v > 0.f ? v : __expf(v) - 1.f;
  }
  if (OUTBF) {
    us4 pk;
#pragma unroll
    for (int r = 0; r < 4; ++r) pk[r] = (unsigned short)fbf(a[r]);
    *(us4*)((unsigned short*)outp + o) = pk;
  } else {
    *(f32x4*)((float*)outp + o) = a;
  }
}

// ---------------------------------------------------------------------------
extern "C" void kernel_launch(void* const* d_in, const int* in_sizes, int n_in,
                              void* d_out, int out_size, void* d_ws, size_t ws_size,
                              hipStream_t stream) {
  const float* chems = (const float*)d_in[0];  // [H, N, 128]
  const int*   adj   = (const int*)d_in[1];    // [N, N]
  const float* W1    = (const float*)d_in[2];  // [H, 128, 128]
  const float* a1    = (const float*)d_in[3];  // [H, 256]
  const float* W2    = (const float*)d_in[4];  // [H, 512, 128]
  const float* a2    = (const float*)d_in[5];  // [H, 256]
  float* out = (float*)d_out;                  // [N, 512] fp32

  char* p = (char*)d_ws;
  auto alloc = [&](size_t bytes) { char* r = p; p += (bytes + 255) & ~255ull; return r; };
  ull*   mbT  = (ull*)alloc((size_t)NW * NN * 8);                        // 2 MB
  unsigned short* cbf  = (unsigned short*)alloc((size_t)HH * NN * DD * 2);   // 4 MB
  unsigned short* xbf  = (unsigned short*)alloc((size_t)NN * HH * DD * 2);   // 4 MB
  unsigned short* WhT1 = (unsigned short*)alloc((size_t)HH * 64 * 8192 * 2); // 4 MB
  unsigned short* WhT2 = (unsigned short*)alloc((size_t)HH * 64 * 8192 * 2); // 4 MB
  unsigned short* WT1  = (unsigned short*)alloc((size_t)HH * 2 * 8192 * 2);  // 128 KB
  unsigned short* WT2  = (unsigned short*)alloc((size_t)HH * 8 * 8192 * 2);  // 512 KB
  float* parts = (float*)alloc((size_t)2 * HH * NN * 128 * 4);           // 16 MB (reused)
  float* sums  = (float*)alloc((size_t)2 * HH * NN * 4);                 // 128 KB
  float* src1 = (float*)alloc((size_t)HH * NN * 4);
  float* dst1 = (float*)alloc((size_t)HH * NN * 4);
  float* src2 = (float*)alloc((size_t)HH * NN * 4);
  float* dst2 = (float*)alloc((size_t)HH * NN * 4);
  (void)ws_size; (void)in_sizes; (void)n_in; (void)out_size;

  pack_mask_kernel<<<NN, 256, 0, stream>>>(adj, mbT);
  cvt_bf16_kernel<<<(HH * NN * DD / 8 + 255) / 256, 256, 0, stream>>>(chems, cbf,
                                                                      HH * NN * DD / 8);
  prep_w_kernel<<<(HH * 2 * 1024 + 255) / 256, 256, 0, stream>>>(W1, WT1, 2);
  prep_w_kernel<<<(HH * 8 * 1024 + 255) / 256, 256, 0, stream>>>(W2, WT2, 8);

  const int FUSE_BLK = (HH * NN * DD / 4) / 256;  // 2048

  // ---- stage 1 ----
  gemm_mfma_kernel<<<dim3(NN / 64, HH), 512, 0, stream>>>(
      cbf, DD, (long)NN * DD, WT1, 2, WhT1, a1, src1, dst1);
  att_part_kernel<<<dim3(2 * NN / 64, HH), 256, 0, stream>>>(
      WhT1, src1, dst1, mbT, parts, sums);
  fuse_kernel<1><<<FUSE_BLK, 256, 0, stream>>>(parts, sums, xbf);
  // ---- stage 2 ----
  gemm_mfma_kernel<<<dim3(NN / 64, HH), 512, 0, stream>>>(
      xbf, HH * DD, 0L, WT2, 8, WhT2, a2, src2, dst2);
  att_part_kernel<<<dim3(2 * NN / 64, HH), 256, 0, stream>>>(
      WhT2, src2, dst2, mbT, parts, sums);
  fuse_kernel<0><<<FUSE_BLK, 256, 0, stream>>>(parts, sums, out);
}

// Round 11
// 228.559 us; speedup vs baseline: 2.0550x; 1.1071x over previous
//
#include <hip/hip_runtime.h>
#include <hip/hip_bf16.h>

typedef unsigned long long ull;
typedef __attribute__((ext_vector_type(8))) short short8;
typedef __attribute__((ext_vector_type(8))) unsigned short us8;
typedef __attribute__((ext_vector_type(4))) unsigned short us4;
typedef __attribute__((ext_vector_type(4))) float f32x4;

constexpr int NN = 4096;   // nodes
constexpr int HH = 4;      // heads
constexpr int DD = 128;    // per-head dim
constexpr int NW = 64;     // 64-j tiles (= 64-bit mask words) per row
constexpr int JSPLIT = 4;  // j-range split for att occupancy (4 blocks/CU)
constexpr float L2E = 1.44269504088896f;

// float -> bf16 RTNE (manual; used in cold paths)
__device__ inline unsigned short f2bf(float x) {
  unsigned u = __float_as_uint(x);
  u += 0x7FFFu + ((u >> 16) & 1u);
  return (unsigned short)(u >> 16);
}

// float -> bf16 via native cast (compiler emits v_cvt_pk_bf16_f32 for pairs)
__device__ inline short fbf(float x) {
  __bf16 b = (__bf16)x;
  short r;
  __builtin_memcpy(&r, &b, 2);
  return r;
}

// async 16B global->LDS (DMA; LDS dest = wave-uniform base + lane*16)
__device__ inline void gload16(const void* g, void* l) {
  __builtin_amdgcn_global_load_lds(
      (const __attribute__((address_space(1))) unsigned int*)g,
      (__attribute__((address_space(3))) unsigned int*)l, 16, 0, 0);
}

// ---------------------------------------------------------------------------
// adj (int32) -> transposed bitmask mbT[w][i] (bits j = w*64..w*64+63 of row i)
// ---------------------------------------------------------------------------
__global__ __launch_bounds__(256) void pack_mask_kernel(const int* __restrict__ adj,
                                                        ull* __restrict__ mbT) {
  const int i    = blockIdx.x;
  const int lane = threadIdx.x & 63;
  const int wave = threadIdx.x >> 6;
  for (int w = wave; w < NW; w += 4) {
    int v = adj[(size_t)i * NN + w * 64 + lane];
    ull m = __ballot(v > 0);
    if (lane == 0) mbT[(size_t)w * NN + i] = m;
  }
}

// ---------------------------------------------------------------------------
// fp32 -> bf16 elementwise (8/thread)
// ---------------------------------------------------------------------------
__global__ __launch_bounds__(256) void cvt_bf16_kernel(const float* __restrict__ in,
                                                       unsigned short* __restrict__ out,
                                                       int n8) {
  int i = blockIdx.x * 256 + threadIdx.x;
  if (i >= n8) return;
  f32x4 a = *(const f32x4*)(in + i * 8);
  f32x4 b = *(const f32x4*)(in + i * 8 + 4);
  us8 v;
#pragma unroll
  for (int q = 0; q < 4; ++q) { v[q] = f2bf(a[q]); v[q + 4] = f2bf(b[q]); }
  *(us8*)(out + i * 8) = v;
}

// ---------------------------------------------------------------------------
// W [H][K][128] fp32 -> WT bf16, tile-major swizzled: [h][kt][c][kc^(c&7)][8]
// ---------------------------------------------------------------------------
__global__ __launch_bounds__(256) void prep_w_kernel(const float* __restrict__ W,
                                                     unsigned short* __restrict__ WT,
                                                     int KT) {
  int id = blockIdx.x * 256 + threadIdx.x;
  int total = HH * KT * 128 * 8;
  if (id >= total) return;
  int kc = id & 7;
  int c  = (id >> 3) & 127;
  int kt = (id >> 10) % KT;
  int h  = id / (KT * 1024);
  int K  = KT * 64;
  const float* src = W + ((size_t)h * K + kt * 64 + kc * 8) * 128 + c;
  us8 v;
#pragma unroll
  for (int e = 0; e < 8; ++e) v[e] = f2bf(src[(size_t)e * 128]);
  *(us8*)(WT + (((size_t)(h * KT + kt) * 128 + c) * 64 + ((kc ^ (c & 7)) * 8))) = v;
}

// ---------------------------------------------------------------------------
// MFMA GEMM (validated): Wh = A(bf16) @ W(bf16).
// Outputs WhT (tiled-swizzled bf16) + srcL/dstL = (Wh.a)*log2e  fp32.
// ---------------------------------------------------------------------------
__global__ __launch_bounds__(512) void gemm_mfma_kernel(
    const unsigned short* __restrict__ A, int sA, long hsA,
    const unsigned short* __restrict__ WT, int KT,
    unsigned short* __restrict__ WhT, const float* __restrict__ avec,
    float* __restrict__ srcO, float* __restrict__ dstO) {
  __shared__ unsigned short Al[2][64 * 64];
  __shared__ unsigned short Wl[2][128 * 64];
  __shared__ float sdred[2][64][2];
  const int t   = threadIdx.x;
  const int h   = blockIdx.y;
  const int i0  = blockIdx.x * 64;
  const int l   = t & 63;
  const int wv  = t >> 6;
  const int l15 = l & 15;
  const int l16 = l >> 4;
  const int wr  = (wv >> 1) * 16;
  const int wc  = (wv & 1) * 64;
  const unsigned short* Ab = A + (size_t)h * hsA;
  const unsigned short* Wb = WT + (size_t)h * KT * 8192;

  const int arowA = wv * 8 + (l >> 3);
  const int agA   = l & 7;

  f32x4 acc[4];
#pragma unroll
  for (int cf = 0; cf < 4; ++cf) acc[cf] = (f32x4){0.f, 0.f, 0.f, 0.f};

#define G_STAGE(kt_, b_)                                                          \
  {                                                                               \
    gload16(Ab + (size_t)(i0 + arowA) * sA + (kt_) * 64 + ((agA ^ (arowA & 7)) * 8), \
            &Al[b_][(wv * 64) * 8]);                                              \
    const unsigned short* wt = Wb + (size_t)(kt_)*8192;                           \
    gload16(wt + (size_t)(wv * 64 + l) * 8, &Wl[b_][(wv * 64) * 8]);              \
    gload16(wt + (size_t)(512 + wv * 64 + l) * 8, &Wl[b_][(512 + wv * 64) * 8]);  \
  }

  G_STAGE(0, 0);
  __syncthreads();
  int buf = 0;
  for (int kt = 0; kt < KT; ++kt) {
    if (kt + 1 < KT) G_STAGE(kt + 1, buf ^ 1);
    const int arow = wr + l15;
#pragma unroll
    for (int s = 0; s < 2; ++s) {
      int kc = s * 4 + l16;
      short8 a = *(const short8*)&Al[buf][arow * 64 + ((kc ^ (arow & 7)) * 8)];
#pragma unroll
      for (int cf = 0; cf < 4; ++cf) {
        int c = wc + cf * 16 + l15;
        short8 b = *(const short8*)&Wl[buf][c * 64 + ((kc ^ (c & 7)) * 8)];
        acc[cf] = __builtin_amdgcn_mfma_f32_16x16x32_bf16(a, b, acc[cf], 0, 0, 0);
      }
    }
    __syncthreads();
    buf ^= 1;
  }

  const int wblk = i0 >> 6;
  const int g    = (wr >> 3) + (l16 >> 1);
  const int eoff = (l16 * 4) & 7;
#pragma unroll
  for (int cf = 0; cf < 4; ++cf) {
    int c = wc + cf * 16 + l15;
    us4 pk;
#pragma unroll
    for (int r = 0; r < 4; ++r) pk[r] = f2bf(acc[cf][r]);
    *(us4*)(WhT + (((size_t)(h * 64 + wblk) * 128 + c) * 64 + ((g ^ (c & 7)) * 8) + eoff)) = pk;
  }

  float ps[4] = {0.f, 0.f, 0.f, 0.f}, pd[4] = {0.f, 0.f, 0.f, 0.f};
#pragma unroll
  for (int cf = 0; cf < 4; ++cf) {
    int c = wc + cf * 16 + l15;
    float as = avec[h * 2 * DD + c];
    float ad = avec[h * 2 * DD + DD + c];
#pragma unroll
    for (int r = 0; r < 4; ++r) { ps[r] += acc[cf][r] * as; pd[r] += acc[cf][r] * ad; }
  }
#pragma unroll
  for (int off = 1; off < 16; off <<= 1) {
#pragma unroll
    for (int r = 0; r < 4; ++r) {
      ps[r] += __shfl_xor(ps[r], off, 64);
      pd[r] += __shfl_xor(pd[r], off, 64);
    }
  }
  if (l15 == 0) {
#pragma unroll
    for (int r = 0; r < 4; ++r) {
      sdred[wv & 1][wr + l16 * 4 + r][0] = ps[r];
      sdred[wv & 1][wr + l16 * 4 + r][1] = pd[r];
    }
  }
  __syncthreads();
  if (t < 128) {
    int row = t >> 1, sel = t & 1;
    float v = (sdred[0][row][sel] + sdred[1][row][sel]) * L2E;
    (sel ? dstO : srcO)[(h << 12) + i0 + row] = v;
  }
#undef G_STAGE
}

// ---------------------------------------------------------------------------
// MFMA attention PARTIAL, UNNORMALIZED.  j-range split JSPLIT ways for
// occupancy (4 blocks/CU -> 16 waves/CU).  p computed once per (i,j).
//   part[jq][g][c] = sum_{j in quarter} p_ij Wh[j][c];  sums[jq][g] = sum p.
// s_setprio(1) around MFMA cluster (independent blocks at different phases).
// ---------------------------------------------------------------------------
__global__ __launch_bounds__(256) void att_part_kernel(
    const unsigned short* __restrict__ WhT, const float* __restrict__ sL,
    const float* __restrict__ dL, const ull* __restrict__ mbT,
    float* __restrict__ part, float* __restrict__ sums) {
  __shared__ unsigned short whl[2][128 * 64];  // 32KB dbuf
  const int t   = threadIdx.x;
  const int h   = blockIdx.y;
  const int jq  = blockIdx.x & (JSPLIT - 1);
  const int i0  = (blockIdx.x / JSPLIT) * 64;
  const int l   = t & 63;
  const int wv  = t >> 6;
  const int l15 = l & 15;
  const int l16 = l >> 4;
  const int wr  = wv * 16;
  const int NIT = NW / JSPLIT;  // 16 j-tiles per block

  const int arow  = i0 + wr + l15;
  const int gr    = (h << 12) + arow;
  const float s_i = sL[gr];
  const float* dj = dL + (h << 12);
  const unsigned short* Wt = WhT + (size_t)(h * 64) * 8192;
  const int w0 = jq * NIT;

  f32x4 acc[8];
#pragma unroll
  for (int cf = 0; cf < 8; ++cf) acc[cf] = (f32x4){0.f, 0.f, 0.f, 0.f};
  float psum = 0.f;

#define A_STAGE(w_, b_)                                                    \
  {                                                                        \
    const unsigned short* gt = Wt + (size_t)(w_)*8192;                     \
    gload16(gt + (size_t)(0 * 256 + t) * 8, &whl[b_][(0 * 256 + wv * 64) * 8]); \
    gload16(gt + (size_t)(1 * 256 + t) * 8, &whl[b_][(1 * 256 + wv * 64) * 8]); \
    gload16(gt + (size_t)(2 * 256 + t) * 8, &whl[b_][(2 * 256 + wv * 64) * 8]); \
    gload16(gt + (size_t)(3 * 256 + t) * 8, &whl[b_][(3 * 256 + wv * 64) * 8]); \
  }

  A_STAGE(w0, 0);
  __syncthreads();
  int buf = 0;
  for (int it = 0; it < NIT; ++it) {
    const int w = w0 + it;
    if (it + 1 < NIT) A_STAGE(w + 1, buf ^ 1);
    // P-gen directly into A-frag registers (lane: row=l15, kchunk=l16)
    ull mb = mbT[(size_t)w * NN + arow];
    short8 afr[2];
#pragma unroll
    for (int s = 0; s < 2; ++s) {
      const int bsh = s * 32 + l16 * 8;
      f32x4 d0 = *(const f32x4*)(dj + w * 64 + bsh);
      f32x4 d1 = *(const f32x4*)(dj + w * 64 + bsh + 4);
      unsigned mb8 = (unsigned)((mb >> bsh) & 0xffull);
#pragma unroll
      for (int q = 0; q < 8; ++q) {
        float tt = s_i + ((q < 4) ? d0[q] : d1[q - 4]);
        float z = fmaxf(tt, 0.2f * tt);          // lrelu, homogeneous in log2e
        z = ((mb8 >> q) & 1u) ? z : -1.0e30f;    // masked -> p = 0
        float pf = __builtin_amdgcn_exp2f(z);
        psum += pf;
        afr[s][q] = fbf(pf);
      }
    }
    __builtin_amdgcn_s_setprio(1);
#pragma unroll
    for (int s = 0; s < 2; ++s) {
      int kc = s * 4 + l16;
#pragma unroll
      for (int cf = 0; cf < 8; ++cf) {
        int c = cf * 16 + l15;
        short8 b = *(const short8*)&whl[buf][c * 64 + ((kc ^ (c & 7)) * 8)];
        acc[cf] = __builtin_amdgcn_mfma_f32_16x16x32_bf16(afr[s], b, acc[cf], 0, 0, 0);
      }
    }
    __builtin_amdgcn_s_setprio(0);
    __syncthreads();
    buf ^= 1;
  }
  // row-sum reduce: lanes {l15, l15+16, l15+32, l15+48} hold same row
  psum += __shfl_xor(psum, 16, 64);
  psum += __shfl_xor(psum, 32, 64);
  if (l16 == 0) sums[(size_t)jq * (HH * NN) + gr] = psum;
  // partial store (fp32): D col = l&15, row = (l>>4)*4 + reg
  float* pb = part + ((size_t)jq * (HH * NN) + (h << 12) + i0) * 128;
#pragma unroll
  for (int cf = 0; cf < 8; ++cf) {
#pragma unroll
    for (int r = 0; r < 4; ++r)
      pb[(size_t)(wr + l16 * 4 + r) * 128 + cf * 16 + l15] = acc[cf][r];
  }
#undef A_STAGE
}

// ---------------------------------------------------------------------------
// Fuse: out[node, h*128+c] = elu( (sum_q part_q) / (sum_q sums_q) ).
// OUTBF: bf16 (stage-1 x).
// ---------------------------------------------------------------------------
template <int OUTBF>
__global__ __launch_bounds__(256) void fuse_kernel(const float* __restrict__ part,
                                                   const float* __restrict__ sums,
                                                   void* __restrict__ outp) {
  int idx = blockIdx.x * 256 + threadIdx.x;   // one f32x4 per thread
  int c4 = (idx & 31) * 4;
  int g = idx >> 5;
  int node = g & (NN - 1), h = g >> 12;
  f32x4 a = (f32x4){0.f, 0.f, 0.f, 0.f};
  float den = 0.f;
#pragma unroll
  for (int q = 0; q < JSPLIT; ++q) {
    f32x4 v = *(const f32x4*)(part + ((size_t)q * (HH * NN) + g) * 128 + c4);
#pragma unroll
    for (int r = 0; r < 4; ++r) a[r] += v[r];
    den += sums[(size_t)q * (HH * NN) + g];
  }
  float inv = 1.0f / den;
  size_t o = (size_t)node * (HH * DD) + h * DD + c4;
#pragma unroll
  for (int r = 0; r < 4; ++r) {
    float v = a[r] * inv;
    a[r] = v > 0.f ? v : __expf(v) - 1.f;
  }
  if (OUTBF) {
    us4 pk;
#pragma unroll
    for (int r = 0; r < 4; ++r) pk[r] = (unsigned short)fbf(a[r]);
    *(us4*)((unsigned short*)outp + o) = pk;
  } else {
    *(f32x4*)((float*)outp + o) = a;
  }
}

// ---------------------------------------------------------------------------
extern "C" void kernel_launch(void* const* d_in, const int* in_sizes, int n_in,
                              void* d_out, int out_size, void* d_ws, size_t ws_size,
                              hipStream_t stream) {
  const float* chems = (const float*)d_in[0];  // [H, N, 128]
  const int*   adj   = (const int*)d_in[1];    // [N, N]
  const float* W1    = (const float*)d_in[2];  // [H, 128, 128]
  const float* a1    = (const float*)d_in[3];  // [H, 256]
  const float* W2    = (const float*)d_in[4];  // [H, 512, 128]
  const float* a2    = (const float*)d_in[5];  // [H, 256]
  float* out = (float*)d_out;                  // [N, 512] fp32

  char* p = (char*)d_ws;
  auto alloc = [&](size_t bytes) { char* r = p; p += (bytes + 255) & ~255ull; return r; };
  ull*   mbT  = (ull*)alloc((size_t)NW * NN * 8);                        // 2 MB
  unsigned short* cbf  = (unsigned short*)alloc((size_t)HH * NN * DD * 2);   // 4 MB
  unsigned short* xbf  = (unsigned short*)alloc((size_t)NN * HH * DD * 2);   // 4 MB
  unsigned short* WhT1 = (unsigned short*)alloc((size_t)HH * 64 * 8192 * 2); // 4 MB
  unsigned short* WhT2 = (unsigned short*)alloc((size_t)HH * 64 * 8192 * 2); // 4 MB
  unsigned short* WT1  = (unsigned short*)alloc((size_t)HH * 2 * 8192 * 2);  // 128 KB
  unsigned short* WT2  = (unsigned short*)alloc((size_t)HH * 8 * 8192 * 2);  // 512 KB
  float* parts = (float*)alloc((size_t)JSPLIT * HH * NN * 128 * 4);      // 32 MB (reused)
  float* sums  = (float*)alloc((size_t)JSPLIT * HH * NN * 4);            // 256 KB
  float* src1 = (float*)alloc((size_t)HH * NN * 4);
  float* dst1 = (float*)alloc((size_t)HH * NN * 4);
  float* src2 = (float*)alloc((size_t)HH * NN * 4);
  float* dst2 = (float*)alloc((size_t)HH * NN * 4);
  (void)ws_size; (void)in_sizes; (void)n_in; (void)out_size;

  pack_mask_kernel<<<NN, 256, 0, stream>>>(adj, mbT);
  cvt_bf16_kernel<<<(HH * NN * DD / 8 + 255) / 256, 256, 0, stream>>>(chems, cbf,
                                                                      HH * NN * DD / 8);
  prep_w_kernel<<<(HH * 2 * 1024 + 255) / 256, 256, 0, stream>>>(W1, WT1, 2);
  prep_w_kernel<<<(HH * 8 * 1024 + 255) / 256, 256, 0, stream>>>(W2, WT2, 8);

  const int FUSE_BLK = (HH * NN * DD / 4) / 256;  // 2048

  // ---- stage 1 ----
  gemm_mfma_kernel<<<dim3(NN / 64, HH), 512, 0, stream>>>(
      cbf, DD, (long)NN * DD, WT1, 2, WhT1, a1, src1, dst1);
  att_part_kernel<<<dim3(JSPLIT * NN / 64, HH), 256, 0, stream>>>(
      WhT1, src1, dst1, mbT, parts, sums);
  fuse_kernel<1><<<FUSE_BLK, 256, 0, stream>>>(parts, sums, xbf);
  // ---- stage 2 ----
  gemm_mfma_kernel<<<dim3(NN / 64, HH), 512, 0, stream>>>(
      xbf, HH * DD, 0L, WT2, 8, WhT2, a2, src2, dst2);
  att_part_kernel<<<dim3(JSPLIT * NN / 64, HH), 256, 0, stream>>>(
      WhT2, src2, dst2, mbT, parts, sums);
  fuse_kernel<0><<<FUSE_BLK, 256, 0, stream>>>(parts, sums, out);
}